// Round 11
// baseline (125.477 us; speedup 1.0000x reference)
//
#include <hip/hip_runtime.h>
#include <hip/hip_fp16.h>

#define D 512
#define NTOK 512
#define BINS 64

typedef float v4f __attribute__((ext_vector_type(4)));
typedef int v4i __attribute__((ext_vector_type(4)));
typedef short short8 __attribute__((ext_vector_type(8)));
typedef _Float16 h8 __attribute__((ext_vector_type(8)));

// packed f16 gelu, trans-minimized (2 transcendentals per half2 vs 4).
// Retest of r4's form in the ISSUE-BOUND regime (r4 tested it latency-bound,
// where VALU savings were invisible). a=|x|; q=-(2.3022082+0.1029437a^2)a<=0;
// e=2^q in (0,1]; sigma=1/(1+e) ~= 1+e*n'(e), n' cubic Chebyshev on [0,1]
// (|err|<=1.2e-3*e -> gelu abs err ~2.8e-4, below f16 quantum of h).
// Sign fold exact: min(x,0) = (x-|x|)*0.5. Tails exact (e->0 => sigma=1).
__device__ __forceinline__ __half2 gelu2(__half2 x) {
    __half2 a = __builtin_bit_cast(__half2, __builtin_bit_cast(int, x) & 0x7fff7fff);
    __half2 s = __hmul2(a, a);
    __half2 m = __hfma2(s, __float2half2_rn(-0.1029437f),
                           __float2half2_rn(-2.3022082f));
    __half2 q = __hmul2(a, m);
    __half2 e = h2exp2(q);                     // (0, 1]
    __half2 n = __hfma2(e, __float2half2_rn(0.228584f),  __float2half2_rn(-0.675920f));
    n = __hfma2(e, n, __float2half2_rn(0.946902f));
    n = __hfma2(e, n, __float2half2_rn(-0.998521f));
    __half2 p = __hfma2(e, n, __float2half2_rn(1.0f));   // sigma = 1 + e*n'
    __half2 xneg = __hmul2(__hsub2(x, a), __float2half2_rn(0.5f));  // min(x,0)
    return __hfma2(a, p, xneg);
}

__device__ __forceinline__ __half2 bc_h2(int v) { return __builtin_bit_cast(__half2, v); }
__device__ __forceinline__ int bc_i(__half2 v) { return __builtin_bit_cast(int, v); }

__device__ __forceinline__ v4i pack8(v4f a, v4f b) {
    h8 o;
    o[0] = (_Float16)a.x; o[1] = (_Float16)a.y; o[2] = (_Float16)a.z; o[3] = (_Float16)a.w;
    o[4] = (_Float16)b.x; o[5] = (_Float16)b.y; o[6] = (_Float16)b.z; o[7] = (_Float16)b.w;
    return __builtin_bit_cast(v4i, o);
}

// DMA 16B global -> LDS (wave-uniform LDS base + lane*16 implicit scatter).
__device__ __forceinline__ void g2lds16(const void* g, void* l) {
    __builtin_amdgcn_global_load_lds(
        (const __attribute__((address_space(1))) void*)g,
        (__attribute__((address_space(3))) void*)l, 16, 0, 0);
}

#define WAITVM_(N) asm volatile("s_waitcnt vmcnt(" #N ")" ::: "memory")
#define WAITVM(N) WAITVM_(N)

// ---- k_pack: operand packing (unchanged).
__global__ __launch_bounds__(256) void k_pack(const float* __restrict__ x,
                                              const float* __restrict__ W1,
                                              const float* __restrict__ W2,
                                              v4i* __restrict__ Ap,
                                              v4i* __restrict__ Wp,
                                              short8* __restrict__ Bp) {
    const int b = blockIdx.x;
    const int t = threadIdx.x;
    if (b < 32) {            // x fragments: 32 rb x 16 ks x 64 lanes
        const int rb = b;
#pragma unroll
        for (int u = 0; u < 4; ++u) {
            const int e = t + 256 * u;           // 0..1023
            const int l = e & 63, ks = e >> 6;
            const float* src = x + (size_t)(rb * 16 + (l & 15)) * D + ks * 32 + (l >> 4) * 8;
            v4f a = *(const v4f*)src;
            v4f c = *(const v4f*)(src + 4);
            Ap[(size_t)(rb * 16 + ks) * 64 + l] = pack8(a, c);
        }
    } else if (b < 288) {    // W1 fragments: one slot per thread
        const int slot = (b - 32) * 256 + t;     // 0..65535
        const int l = slot & 63;
        const int ks = (slot >> 6) & 15;
        const int nb = slot >> 10;               // 0..63
        const int ng = nb * 16 + (l & 15);       // combined out col 0..1023
        const float* src = W1 + (size_t)((ng >> 9) * D + ks * 32 + (l >> 4) * 8) * D
                              + (ng & 511);
        h8 o;
#pragma unroll
        for (int j = 0; j < 8; ++j) o[j] = (_Float16)src[(size_t)j * D];  // RTE
        Wp[(size_t)(nb * 16 + ks) * 64 + l] = __builtin_bit_cast(v4i, o);
    } else {                 // W2 -> Bp
        const int tid = (b - 288) * 256 + t;     // 0..4095
        const int ll = tid & 63;
        const int nt = (tid >> 6) & 3;
        const int kt = tid >> 8;
        const int colp = nt * 16 + (ll & 15);
        const int krow = kt * 32 + (ll >> 4) * 8;
        short8 v;
#pragma unroll
        for (int u = 0; u < 8; ++u) {
            _Float16 hv = (_Float16)W2[(size_t)(krow + u) * BINS + colp];  // RTE
            v[u] = __builtin_bit_cast(short, hv);
        }
        Bp[tid] = v;
    }
}

// ---- k_gemm: projection GEMM (unchanged).
__global__ __launch_bounds__(256) void k_gemm(const v4i* __restrict__ Ap,
                                              const v4i* __restrict__ Wp,
                                              const float* __restrict__ b1,
                                              _Float16* __restrict__ hi,
                                              _Float16* __restrict__ hj) {
    const int l = threadIdx.x & 63;
    const int w = threadIdx.x >> 6;
    const int c = l & 15;
    const int q = l >> 4;
    const int mb = blockIdx.x >> 4;              // 0..31
    const int cb = blockIdx.x & 15;
    const int nb = cb * 4 + w;

    const v4i* ap = Ap + (size_t)mb * 16 * 64 + l;
    const v4i* wp = Wp + (size_t)nb * 16 * 64 + l;

    v4f acc = {0.f, 0.f, 0.f, 0.f};
#pragma unroll
    for (int ks = 0; ks < 16; ++ks) {
        v4i a0 = ap[ks * 64];
        v4i bb = wp[ks * 64];
        acc = __builtin_amdgcn_mfma_f32_16x16x32_f16(__builtin_bit_cast(h8, a0),
                                                     __builtin_bit_cast(h8, bb), acc, 0, 0, 0);
    }

    const int ng = nb * 16 + c;
    const float b1v = (ng < D) ? b1[ng] : 0.0f;
    _Float16* dst = (ng < D ? hi : hj) + (ng & 511);
    const int row0 = mb * 16 + q * 4;
#pragma unroll
    for (int r = 0; r < 4; ++r)
        dst[(size_t)(row0 + r) * D] = (_Float16)(acc[r] + b1v);
}

// ---- k_main: r10 structure byte-identical (16x16 tile, acc[4][4], grid 1024,
// 4 blocks/CU, 8 fat phases x 2 kt, NBUF=6 counted-vmcnt DMA ring). ONLY
// change this round: gelu2 -> trans-minimized form (single-variable retest
// in the issue-bound regime; r4's null was measured latency-bound).
#define NBUF 6
#define BUFSZ 6144
__global__ __launch_bounds__(256, 4) void k_main(const __half* __restrict__ hi,
                                                 const __half* __restrict__ hj,
                                                 const float* __restrict__ b2,
                                                 const char* __restrict__ BpB,
                                                 float* __restrict__ out) {
    const int l = threadIdx.x & 63;
    const int w = threadIdx.x >> 6;
    const int c = l & 15;   // MFMA col: A m-index (j-offset) / B,D n-offset
    const int q = l >> 4;   // quad: k-group for A/B, row-group for D
    const int ib = (blockIdx.x >> 5) * 16;
    const int j0 = (blockIdx.x & 31) * 16;

    __shared__ __align__(16) char lds[NBUF * BUFSZ];   // 36864 B

    const char* hjB = (const char*)hj;
    const char* hiB = (const char*)hi;

    // stage tile kt into ring buffer bi: wave w -> Bp slots w*64.., 16B/lane.
    // wave 0 also stages hj (lane l <-> row j0+(l&15), 16B unit (l>>4));
    // wave 1 stages hi (lane l <-> row ib+(l>>2), 16B unit (l&3)).
#define STAGE(kt_, bi_)                                                          \
    {                                                                            \
        char* buf_ = lds + (bi_) * BUFSZ;                                        \
        g2lds16(BpB + (size_t)(kt_) * 4096 + (w * 64 + l) * 16, buf_ + w * 1024);\
        if (w == 0)                                                              \
            g2lds16(hjB + (size_t)(j0 + (l & 15)) * 1024 + (kt_) * 64 + (l >> 4) * 16, \
                    buf_ + 4096);                                                \
        if (w == 1)                                                              \
            g2lds16(hiB + (size_t)(ib + (l >> 2)) * 1024 + (kt_) * 64 + (l & 3) * 16,  \
                    buf_ + 5120);                                                \
    }

    v4f acc[4][4] = {};  // [p(i)][nt]

    STAGE(0, 0) STAGE(1, 1)

#pragma unroll
    for (int ph = 0; ph < 8; ++ph) {
        const int kt0 = ph * 2;
        if (ph < 7) { STAGE(kt0 + 2, (kt0 + 2) % NBUF) STAGE(kt0 + 3, (kt0 + 3) % NBUF) }
        if (ph < 7) {
            if (w < 2) WAITVM(4); else WAITVM(2);
        } else {
            WAITVM(0);
        }
        __builtin_amdgcn_s_barrier();

#pragma unroll
        for (int kk = 0; kk < 2; ++kk) {
            const int kt = kt0 + kk;
            const char* buf = lds + (kt % NBUF) * BUFSZ;
            const v4i* bsec = (const v4i*)buf;           // Bp: slot nt*64 + l
            v4i bfr[4];
#pragma unroll
            for (int nt = 0; nt < 4; ++nt) bfr[nt] = bsec[nt * 64 + l];
            v4i hjraw = ((const v4i*)(buf + 4096))[l];
            __half2 j0h = bc_h2(hjraw.x), j1h = bc_h2(hjraw.y);
            __half2 j2h = bc_h2(hjraw.z), j3h = bc_h2(hjraw.w);
#pragma unroll
            for (int p = 0; p < 4; ++p) {
                v4i ar = *(const v4i*)(buf + 5120 + ((w * 4 + p) * 4 + q) * 16);
                __half2 g0 = gelu2(__hadd2(bc_h2(ar.x), j0h));
                __half2 g1 = gelu2(__hadd2(bc_h2(ar.y), j1h));
                __half2 g2 = gelu2(__hadd2(bc_h2(ar.z), j2h));
                __half2 g3 = gelu2(__hadd2(bc_h2(ar.w), j3h));
                v4i ai = {bc_i(g0), bc_i(g1), bc_i(g2), bc_i(g3)};
                h8 af = __builtin_bit_cast(h8, ai);
#pragma unroll
                for (int nt = 0; nt < 4; ++nt)
                    acc[p][nt] = __builtin_amdgcn_mfma_f32_16x16x32_f16(
                        af, __builtin_bit_cast(h8, bfr[nt]), acc[p][nt], 0, 0, 0);
            }
        }
    }
#undef STAGE

    const int i0 = ib + w * 4;
#pragma unroll
    for (int p = 0; p < 4; ++p) {
        const size_t rowbase = ((size_t)(i0 + p) * NTOK + j0 + q * 4) * BINS;
#pragma unroll
        for (int nt = 0; nt < 4; ++nt) {
            const float bb = b2[nt * 16 + c];
            float* op = out + rowbase + nt * 16 + c;
#pragma unroll
            for (int rr = 0; rr < 4; ++rr)
                op[(size_t)rr * BINS] = acc[p][nt][rr] + bb;
        }
    }
}

extern "C" void kernel_launch(void* const* d_in, const int* in_sizes, int n_in,
                              void* d_out, int out_size, void* d_ws, size_t ws_size,
                              hipStream_t stream) {
    const float* x  = (const float*)d_in[0];
    const float* W1 = (const float*)d_in[1];
    const float* b1 = (const float*)d_in[2];
    const float* W2 = (const float*)d_in[3];
    const float* b2 = (const float*)d_in[4];
    float* out = (float*)d_out;

    char* ws = (char*)d_ws;
    __half* hi = (__half*)ws;                          // 512 KB
    __half* hj = (__half*)(ws + (512u << 10));         // 512 KB
    short8* Bp = (short8*)(ws + (1u << 20));           // 64 KB
    v4i*    Ap = (v4i*)(ws + (1u << 20) + (64u << 10));            // 512 KB
    v4i*    Wp = (v4i*)(ws + (1u << 20) + (64u << 10) + (512u << 10));  // 1 MB

    k_pack<<<304, 256, 0, stream>>>(x, W1, W2, Ap, Wp, Bp);
    k_gemm<<<512, 256, 0, stream>>>(Ap, Wp, b1, (_Float16*)hi, (_Float16*)hj);
    k_main<<<1024, 256, 0, stream>>>(hi, hj, b2, (const char*)Bp, out);
}

// Round 13
// 122.438 us; speedup vs baseline: 1.0248x; 1.0248x over previous
//
#include <hip/hip_runtime.h>
#include <hip/hip_fp16.h>

#define D 512
#define NTOK 512
#define BINS 64

typedef float v4f __attribute__((ext_vector_type(4)));
typedef int v4i __attribute__((ext_vector_type(4)));
typedef short short8 __attribute__((ext_vector_type(8)));
typedef _Float16 h8 __attribute__((ext_vector_type(8)));

// packed f16 tanh-approx gelu: x * sigmoid(1.5957691x + 0.0713548x^3), exp2
// form, 9 issue slots (r11: beats the 12-slot trans-min form — issue slots
// are the currency). f16 saturation gives exact limits.
__device__ __forceinline__ __half2 gelu2(__half2 x) {
    __half2 s = __hmul2(x, x);
    __half2 q = __hmul2(x, __hfma2(s, __float2half2_rn(-0.1029437f),
                                      __float2half2_rn(-2.3022082f)));
    __half2 e = h2exp2(q);
    __half2 r = h2rcp(__hadd2(e, __float2half2_rn(1.0f)));
    return __hmul2(x, r);
}

__device__ __forceinline__ __half2 bc_h2(int v) { return __builtin_bit_cast(__half2, v); }
__device__ __forceinline__ int bc_i(__half2 v) { return __builtin_bit_cast(int, v); }

// DMA 16B global -> LDS (wave-uniform LDS base + lane*16 implicit scatter;
// GLOBAL source address is per-lane — scattered gathers allowed).
__device__ __forceinline__ void g2lds16(const void* g, void* l) {
    __builtin_amdgcn_global_load_lds(
        (const __attribute__((address_space(1))) void*)g,
        (__attribute__((address_space(3))) void*)l, 16, 0, 0);
}

#define WAITVM_(N) asm volatile("s_waitcnt vmcnt(" #N ")" ::: "memory")
#define WAITVM(N) WAITVM_(N)

// ---- k_proj: single staged MFMA GEMM replacing k_pack+k_gemm.
// H[512 m, 1024 ncomb] = x @ [W1a|W1b]; hi gets +b1. Blocks 0..511:
// gm=b>>4 (16 m-rows), gn=b&15 (64 n-cols; gn<8 -> W1a, else W1b).
// K in 8 chunks of 64; NBUF=3 ring (20KB/chunk: X-frags 4KB + W rows 16KB),
// stage-ahead 1, counted vmcnt (5 instrs/wave/STAGE), 1 raw barrier/chunk.
//  X staged in A-FRAGMENT order: instr i (=wave w), lane l reads global
//   x[m0+(l&15)][c*64 + (i>>1)*32 + (l>>4)*8 + (i&1)*4 ..+4] -> LDS i*1024+l*16;
//   reader: canonical conflict-free b128 at ks*2048(+1024)+l*16.
//  W staged row-major with unit-XOR swizzle u' = u ^ ((kr>>3)&7) (both-sides:
//   pre-swizzled global col + swizzled b32 read -> 2-way banks = free).
// Blocks 512..527: W2 -> Bp fragment pack (unchanged layout).
__global__ __launch_bounds__(256, 2) void k_proj(const float* __restrict__ x,
                                                 const float* __restrict__ W1,
                                                 const float* __restrict__ b1,
                                                 const float* __restrict__ W2,
                                                 _Float16* __restrict__ hi,
                                                 _Float16* __restrict__ hj,
                                                 short8* __restrict__ Bp) {
    const int b = blockIdx.x;
    const int t = threadIdx.x;
    if (b >= 512) {          // W2 -> Bp
        const int tid = (b - 512) * 256 + t;     // 0..4095
        const int ll = tid & 63;
        const int nt = (tid >> 6) & 3;
        const int kt = tid >> 8;
        const int colp = nt * 16 + (ll & 15);
        const int krow = kt * 32 + (ll >> 4) * 8;
        short8 v;
#pragma unroll
        for (int u = 0; u < 8; ++u) {
            _Float16 hv = (_Float16)W2[(size_t)(krow + u) * BINS + colp];  // RTE
            v[u] = __builtin_bit_cast(short, hv);
        }
        Bp[tid] = v;
        return;
    }
    const int l = t & 63;
    const int w = t >> 6;
    const int c = l & 15;
    const int q = l >> 4;
    const int gm = b >> 4;                   // 0..31 -> m0
    const int gn = b & 15;                   // 0..15 -> 64-col tile
    const int m0 = gm * 16;
    const int halfBase = (gn >> 3) * 512;    // W1 row base
    const int ncol0 = (gn & 7) * 64;         // col base within half
    const int nn = w * 16 + c;               // 0..63 within tile

    __shared__ __align__(16) char lds[3 * 20480];   // 61440 B

    // stage chunk c_ into ring buffer bi_: each wave issues exactly 5 DMAs.
#define PSTAGE(c_, bi_)                                                           \
    {                                                                             \
        char* buf_ = lds + (bi_) * 20480;                                         \
        g2lds16(x + (size_t)(m0 + (l & 15)) * 512 + (c_) * 64                     \
                    + (w >> 1) * 32 + (l >> 4) * 8 + (w & 1) * 4,                 \
                buf_ + w * 1024);                                                 \
        _Pragma("unroll")                                                         \
        for (int jj = 0; jj < 4; ++jj) {                                          \
            const int j_ = w * 4 + jj;                                            \
            g2lds16(W1 + (size_t)(halfBase + (c_) * 64 + j_ * 4 + (l >> 4)) * 512 \
                        + ncol0 + (((l & 15) ^ ((j_ >> 1) & 7)) << 2),            \
                    buf_ + 4096 + j_ * 1024);                                     \
        }                                                                         \
    }

    // swizzled col-byte within a W row, per ks (unit = nn>>2 ^ ((ks*4+q)&7))
    const int cb0 = ((((nn >> 2) ^ (q & 7)) << 4) | ((nn & 3) << 2));
    const int cb1 = ((((nn >> 2) ^ ((4 + q) & 7)) << 4) | ((nn & 3) << 2));

    v4f acc = {0.f, 0.f, 0.f, 0.f};

    PSTAGE(0, 0)
#pragma unroll
    for (int ch = 0; ch < 8; ++ch) {
        if (ch < 7) PSTAGE(ch + 1, (ch + 1) % 3)
        if (ch < 7) WAITVM(5); else WAITVM(0);
        __builtin_amdgcn_s_barrier();

        const char* buf = lds + (ch % 3) * 20480;
#pragma unroll
        for (int ks = 0; ks < 2; ++ks) {
            v4f a0 = *(const v4f*)(buf + ks * 2048 + l * 16);
            v4f a1 = *(const v4f*)(buf + ks * 2048 + 1024 + l * 16);
            h8 af;
            af[0] = (_Float16)a0.x; af[1] = (_Float16)a0.y;
            af[2] = (_Float16)a0.z; af[3] = (_Float16)a0.w;
            af[4] = (_Float16)a1.x; af[5] = (_Float16)a1.y;
            af[6] = (_Float16)a1.z; af[7] = (_Float16)a1.w;
            const char* wb = buf + 4096 + (ks * 32 + q * 8) * 256
                           + (ks ? cb1 : cb0);
            h8 bf;
#pragma unroll
            for (int j = 0; j < 8; ++j)
                bf[j] = (_Float16)(*(const float*)(wb + j * 256));  // RTE
            acc = __builtin_amdgcn_mfma_f32_16x16x32_f16(af, bf, acc, 0, 0, 0);
        }
    }
#undef PSTAGE

    const float b1v = (gn < 8) ? b1[ncol0 + nn] : 0.0f;
    _Float16* dst = (gn < 8 ? hi : hj) + ncol0 + nn;
#pragma unroll
    for (int r = 0; r < 4; ++r)
        dst[(size_t)(m0 + q * 4 + r) * 512] = (_Float16)(acc[r] + b1v);
}

// ---- k_main: r10 exact (best measured: 48.9us). 16x16 tile, acc[4][4],
// grid 1024, 4 blocks/CU, 8 fat phases x 2 kt, NBUF=6 counted-vmcnt DMA ring,
// 9-inst sigmoid gelu (r11's trans-min regressed; reverted).
#define NBUF 6
#define BUFSZ 6144
__global__ __launch_bounds__(256, 4) void k_main(const __half* __restrict__ hi,
                                                 const __half* __restrict__ hj,
                                                 const float* __restrict__ b2,
                                                 const char* __restrict__ BpB,
                                                 float* __restrict__ out) {
    const int l = threadIdx.x & 63;
    const int w = threadIdx.x >> 6;
    const int c = l & 15;   // MFMA col: A m-index (j-offset) / B,D n-offset
    const int q = l >> 4;   // quad: k-group for A/B, row-group for D
    const int ib = (blockIdx.x >> 5) * 16;
    const int j0 = (blockIdx.x & 31) * 16;

    __shared__ __align__(16) char lds[NBUF * BUFSZ];   // 36864 B

    const char* hjB = (const char*)hj;
    const char* hiB = (const char*)hi;

#define STAGE(kt_, bi_)                                                          \
    {                                                                            \
        char* buf_ = lds + (bi_) * BUFSZ;                                        \
        g2lds16(BpB + (size_t)(kt_) * 4096 + (w * 64 + l) * 16, buf_ + w * 1024);\
        if (w == 0)                                                              \
            g2lds16(hjB + (size_t)(j0 + (l & 15)) * 1024 + (kt_) * 64 + (l >> 4) * 16, \
                    buf_ + 4096);                                                \
        if (w == 1)                                                              \
            g2lds16(hiB + (size_t)(ib + (l >> 2)) * 1024 + (kt_) * 64 + (l & 3) * 16,  \
                    buf_ + 5120);                                                \
    }

    v4f acc[4][4] = {};  // [p(i)][nt]

    STAGE(0, 0) STAGE(1, 1)

#pragma unroll
    for (int ph = 0; ph < 8; ++ph) {
        const int kt0 = ph * 2;
        if (ph < 7) { STAGE(kt0 + 2, (kt0 + 2) % NBUF) STAGE(kt0 + 3, (kt0 + 3) % NBUF) }
        if (ph < 7) {
            if (w < 2) WAITVM(4); else WAITVM(2);
        } else {
            WAITVM(0);
        }
        __builtin_amdgcn_s_barrier();

#pragma unroll
        for (int kk = 0; kk < 2; ++kk) {
            const int kt = kt0 + kk;
            const char* buf = lds + (kt % NBUF) * BUFSZ;
            const v4i* bsec = (const v4i*)buf;           // Bp: slot nt*64 + l
            v4i bfr[4];
#pragma unroll
            for (int nt = 0; nt < 4; ++nt) bfr[nt] = bsec[nt * 64 + l];
            v4i hjraw = ((const v4i*)(buf + 4096))[l];
            __half2 j0h = bc_h2(hjraw.x), j1h = bc_h2(hjraw.y);
            __half2 j2h = bc_h2(hjraw.z), j3h = bc_h2(hjraw.w);
#pragma unroll
            for (int p = 0; p < 4; ++p) {
                v4i ar = *(const v4i*)(buf + 5120 + ((w * 4 + p) * 4 + q) * 16);
                __half2 g0 = gelu2(__hadd2(bc_h2(ar.x), j0h));
                __half2 g1 = gelu2(__hadd2(bc_h2(ar.y), j1h));
                __half2 g2 = gelu2(__hadd2(bc_h2(ar.z), j2h));
                __half2 g3 = gelu2(__hadd2(bc_h2(ar.w), j3h));
                v4i ai = {bc_i(g0), bc_i(g1), bc_i(g2), bc_i(g3)};
                h8 af = __builtin_bit_cast(h8, ai);
#pragma unroll
                for (int nt = 0; nt < 4; ++nt)
                    acc[p][nt] = __builtin_amdgcn_mfma_f32_16x16x32_f16(
                        af, __builtin_bit_cast(h8, bfr[nt]), acc[p][nt], 0, 0, 0);
            }
        }
    }
#undef STAGE

    const int i0 = ib + w * 4;
#pragma unroll
    for (int p = 0; p < 4; ++p) {
        const size_t rowbase = ((size_t)(i0 + p) * NTOK + j0 + q * 4) * BINS;
#pragma unroll
        for (int nt = 0; nt < 4; ++nt) {
            const float bb = b2[nt * 16 + c];
            float* op = out + rowbase + nt * 16 + c;
#pragma unroll
            for (int rr = 0; rr < 4; ++rr)
                op[(size_t)rr * BINS] = acc[p][nt][rr] + bb;
        }
    }
}

extern "C" void kernel_launch(void* const* d_in, const int* in_sizes, int n_in,
                              void* d_out, int out_size, void* d_ws, size_t ws_size,
                              hipStream_t stream) {
    const float* x  = (const float*)d_in[0];
    const float* W1 = (const float*)d_in[1];
    const float* b1 = (const float*)d_in[2];
    const float* W2 = (const float*)d_in[3];
    const float* b2 = (const float*)d_in[4];
    float* out = (float*)d_out;

    char* ws = (char*)d_ws;
    _Float16* hi = (_Float16*)ws;                      // 512 KB
    _Float16* hj = (_Float16*)(ws + (512u << 10));     // 512 KB
    short8*   Bp = (short8*)(ws + (1u << 20));         // 64 KB

    k_proj<<<528, 256, 0, stream>>>(x, W1, b1, W2, hi, hj, Bp);
    k_main<<<1024, 256, 0, stream>>>((const __half*)hi, (const __half*)hj, b2,
                                     (const char*)Bp, out);
}

// Round 14
// 121.290 us; speedup vs baseline: 1.0345x; 1.0095x over previous
//
#include <hip/hip_runtime.h>
#include <hip/hip_fp16.h>

#define D 512
#define NTOK 512
#define BINS 64

typedef float v4f __attribute__((ext_vector_type(4)));
typedef int v4i __attribute__((ext_vector_type(4)));
typedef short short8 __attribute__((ext_vector_type(8)));
typedef _Float16 h8 __attribute__((ext_vector_type(8)));

// packed f16 tanh-approx gelu: x * sigmoid(1.5957691x + 0.0713548x^3), exp2
// form, 9 issue slots (r11: beats the 12-slot trans-min form — issue slots
// are the currency). f16 saturation gives exact limits.
__device__ __forceinline__ __half2 gelu2(__half2 x) {
    __half2 s = __hmul2(x, x);
    __half2 q = __hmul2(x, __hfma2(s, __float2half2_rn(-0.1029437f),
                                      __float2half2_rn(-2.3022082f)));
    __half2 e = h2exp2(q);
    __half2 r = h2rcp(__hadd2(e, __float2half2_rn(1.0f)));
    return __hmul2(x, r);
}

__device__ __forceinline__ __half2 bc_h2(int v) { return __builtin_bit_cast(__half2, v); }
__device__ __forceinline__ int bc_i(__half2 v) { return __builtin_bit_cast(int, v); }

// DMA 16B global -> LDS (wave-uniform LDS base + lane*16 implicit scatter;
// GLOBAL source address is per-lane — scattered gathers allowed).
__device__ __forceinline__ void g2lds16(const void* g, void* l) {
    __builtin_amdgcn_global_load_lds(
        (const __attribute__((address_space(1))) void*)g,
        (__attribute__((address_space(3))) void*)l, 16, 0, 0);
}

#define WAITVM_(N) asm volatile("s_waitcnt vmcnt(" #N ")" ::: "memory")
#define WAITVM(N) WAITVM_(N)

// ---- k_proj: single staged MFMA GEMM (unchanged from r13; ~neutral vs
// pack+gemm but one fewer launch). H = x @ [W1a|W1b]; hi gets +b1.
__global__ __launch_bounds__(256, 2) void k_proj(const float* __restrict__ x,
                                                 const float* __restrict__ W1,
                                                 const float* __restrict__ b1,
                                                 const float* __restrict__ W2,
                                                 _Float16* __restrict__ hi,
                                                 _Float16* __restrict__ hj,
                                                 short8* __restrict__ Bp) {
    const int b = blockIdx.x;
    const int t = threadIdx.x;
    if (b >= 512) {          // W2 -> Bp
        const int tid = (b - 512) * 256 + t;     // 0..4095
        const int ll = tid & 63;
        const int nt = (tid >> 6) & 3;
        const int kt = tid >> 8;
        const int colp = nt * 16 + (ll & 15);
        const int krow = kt * 32 + (ll >> 4) * 8;
        short8 v;
#pragma unroll
        for (int u = 0; u < 8; ++u) {
            _Float16 hv = (_Float16)W2[(size_t)(krow + u) * BINS + colp];  // RTE
            v[u] = __builtin_bit_cast(short, hv);
        }
        Bp[tid] = v;
        return;
    }
    const int l = t & 63;
    const int w = t >> 6;
    const int c = l & 15;
    const int q = l >> 4;
    const int gm = b >> 4;                   // 0..31 -> m0
    const int gn = b & 15;                   // 0..15 -> 64-col tile
    const int m0 = gm * 16;
    const int halfBase = (gn >> 3) * 512;    // W1 row base
    const int ncol0 = (gn & 7) * 64;         // col base within half
    const int nn = w * 16 + c;               // 0..63 within tile

    __shared__ __align__(16) char lds[3 * 20480];   // 61440 B

#define PSTAGE(c_, bi_)                                                           \
    {                                                                             \
        char* buf_ = lds + (bi_) * 20480;                                         \
        g2lds16(x + (size_t)(m0 + (l & 15)) * 512 + (c_) * 64                     \
                    + (w >> 1) * 32 + (l >> 4) * 8 + (w & 1) * 4,                 \
                buf_ + w * 1024);                                                 \
        _Pragma("unroll")                                                         \
        for (int jj = 0; jj < 4; ++jj) {                                          \
            const int j_ = w * 4 + jj;                                            \
            g2lds16(W1 + (size_t)(halfBase + (c_) * 64 + j_ * 4 + (l >> 4)) * 512 \
                        + ncol0 + (((l & 15) ^ ((j_ >> 1) & 7)) << 2),            \
                    buf_ + 4096 + j_ * 1024);                                     \
        }                                                                         \
    }

    const int cb0 = ((((nn >> 2) ^ (q & 7)) << 4) | ((nn & 3) << 2));
    const int cb1 = ((((nn >> 2) ^ ((4 + q) & 7)) << 4) | ((nn & 3) << 2));

    v4f acc = {0.f, 0.f, 0.f, 0.f};

    PSTAGE(0, 0)
#pragma unroll
    for (int ch = 0; ch < 8; ++ch) {
        if (ch < 7) PSTAGE(ch + 1, (ch + 1) % 3)
        if (ch < 7) WAITVM(5); else WAITVM(0);
        __builtin_amdgcn_s_barrier();

        const char* buf = lds + (ch % 3) * 20480;
#pragma unroll
        for (int ks = 0; ks < 2; ++ks) {
            v4f a0 = *(const v4f*)(buf + ks * 2048 + l * 16);
            v4f a1 = *(const v4f*)(buf + ks * 2048 + 1024 + l * 16);
            h8 af;
            af[0] = (_Float16)a0.x; af[1] = (_Float16)a0.y;
            af[2] = (_Float16)a0.z; af[3] = (_Float16)a0.w;
            af[4] = (_Float16)a1.x; af[5] = (_Float16)a1.y;
            af[6] = (_Float16)a1.z; af[7] = (_Float16)a1.w;
            const char* wb = buf + 4096 + (ks * 32 + q * 8) * 256
                           + (ks ? cb1 : cb0);
            h8 bf;
#pragma unroll
            for (int j = 0; j < 8; ++j)
                bf[j] = (_Float16)(*(const float*)(wb + j * 256));  // RTE
            acc = __builtin_amdgcn_mfma_f32_16x16x32_f16(af, bf, acc, 0, 0, 0);
        }
    }
#undef PSTAGE

    const float b1v = (gn < 8) ? b1[ncol0 + nn] : 0.0f;
    _Float16* dst = (gn < 8 ? hi : hj) + ncol0 + nn;
#pragma unroll
    for (int r = 0; r < 4; ++r)
        dst[(size_t)(m0 + q * 4 + r) * 512] = (_Float16)(acc[r] + b1v);
}

// ---- k_main: r13 structure byte-identical EXCEPT s_setprio(1)/(0) around the
// per-phase compute region (T5: pays when co-resident waves have role
// diversity — our 4 blocks/CU sit at different phase positions, so waves in
// gelu+MFMA get CU-scheduler priority over waves issuing DMA/waiting).
#define NBUF 6
#define BUFSZ 6144
__global__ __launch_bounds__(256, 4) void k_main(const __half* __restrict__ hi,
                                                 const __half* __restrict__ hj,
                                                 const float* __restrict__ b2,
                                                 const char* __restrict__ BpB,
                                                 float* __restrict__ out) {
    const int l = threadIdx.x & 63;
    const int w = threadIdx.x >> 6;
    const int c = l & 15;   // MFMA col: A m-index (j-offset) / B,D n-offset
    const int q = l >> 4;   // quad: k-group for A/B, row-group for D
    const int ib = (blockIdx.x >> 5) * 16;
    const int j0 = (blockIdx.x & 31) * 16;

    __shared__ __align__(16) char lds[NBUF * BUFSZ];   // 36864 B

    const char* hjB = (const char*)hj;
    const char* hiB = (const char*)hi;

#define STAGE(kt_, bi_)                                                          \
    {                                                                            \
        char* buf_ = lds + (bi_) * BUFSZ;                                        \
        g2lds16(BpB + (size_t)(kt_) * 4096 + (w * 64 + l) * 16, buf_ + w * 1024);\
        if (w == 0)                                                              \
            g2lds16(hjB + (size_t)(j0 + (l & 15)) * 1024 + (kt_) * 64 + (l >> 4) * 16, \
                    buf_ + 4096);                                                \
        if (w == 1)                                                              \
            g2lds16(hiB + (size_t)(ib + (l >> 2)) * 1024 + (kt_) * 64 + (l & 3) * 16,  \
                    buf_ + 5120);                                                \
    }

    v4f acc[4][4] = {};  // [p(i)][nt]

    STAGE(0, 0) STAGE(1, 1)

#pragma unroll
    for (int ph = 0; ph < 8; ++ph) {
        const int kt0 = ph * 2;
        if (ph < 7) { STAGE(kt0 + 2, (kt0 + 2) % NBUF) STAGE(kt0 + 3, (kt0 + 3) % NBUF) }
        if (ph < 7) {
            if (w < 2) WAITVM(4); else WAITVM(2);
        } else {
            WAITVM(0);
        }
        __builtin_amdgcn_s_barrier();
        __builtin_amdgcn_s_setprio(1);

#pragma unroll
        for (int kk = 0; kk < 2; ++kk) {
            const int kt = kt0 + kk;
            const char* buf = lds + (kt % NBUF) * BUFSZ;
            const v4i* bsec = (const v4i*)buf;           // Bp: slot nt*64 + l
            v4i bfr[4];
#pragma unroll
            for (int nt = 0; nt < 4; ++nt) bfr[nt] = bsec[nt * 64 + l];
            v4i hjraw = ((const v4i*)(buf + 4096))[l];
            __half2 j0h = bc_h2(hjraw.x), j1h = bc_h2(hjraw.y);
            __half2 j2h = bc_h2(hjraw.z), j3h = bc_h2(hjraw.w);
#pragma unroll
            for (int p = 0; p < 4; ++p) {
                v4i ar = *(const v4i*)(buf + 5120 + ((w * 4 + p) * 4 + q) * 16);
                __half2 g0 = gelu2(__hadd2(bc_h2(ar.x), j0h));
                __half2 g1 = gelu2(__hadd2(bc_h2(ar.y), j1h));
                __half2 g2 = gelu2(__hadd2(bc_h2(ar.z), j2h));
                __half2 g3 = gelu2(__hadd2(bc_h2(ar.w), j3h));
                v4i ai = {bc_i(g0), bc_i(g1), bc_i(g2), bc_i(g3)};
                h8 af = __builtin_bit_cast(h8, ai);
#pragma unroll
                for (int nt = 0; nt < 4; ++nt)
                    acc[p][nt] = __builtin_amdgcn_mfma_f32_16x16x32_f16(
                        af, __builtin_bit_cast(h8, bfr[nt]), acc[p][nt], 0, 0, 0);
            }
        }
        __builtin_amdgcn_s_setprio(0);
    }
#undef STAGE

    const int i0 = ib + w * 4;
#pragma unroll
    for (int p = 0; p < 4; ++p) {
        const size_t rowbase = ((size_t)(i0 + p) * NTOK + j0 + q * 4) * BINS;
#pragma unroll
        for (int nt = 0; nt < 4; ++nt) {
            const float bb = b2[nt * 16 + c];
            float* op = out + rowbase + nt * 16 + c;
#pragma unroll
            for (int rr = 0; rr < 4; ++rr)
                op[(size_t)rr * BINS] = acc[p][nt][rr] + bb;
        }
    }
}

extern "C" void kernel_launch(void* const* d_in, const int* in_sizes, int n_in,
                              void* d_out, int out_size, void* d_ws, size_t ws_size,
                              hipStream_t stream) {
    const float* x  = (const float*)d_in[0];
    const float* W1 = (const float*)d_in[1];
    const float* b1 = (const float*)d_in[2];
    const float* W2 = (const float*)d_in[3];
    const float* b2 = (const float*)d_in[4];
    float* out = (float*)d_out;

    char* ws = (char*)d_ws;
    _Float16* hi = (_Float16*)ws;                      // 512 KB
    _Float16* hj = (_Float16*)(ws + (512u << 10));     // 512 KB
    short8*   Bp = (short8*)(ws + (1u << 20));         // 64 KB

    k_proj<<<528, 256, 0, stream>>>(x, W1, b1, W2, hi, hj, Bp);
    k_main<<<1024, 256, 0, stream>>>((const __half*)hi, (const __half*)hj, b2,
                                     (const char*)Bp, out);
}